// Round 10
// baseline (342.129 us; speedup 1.0000x reference)
//
#include <hip/hip_runtime.h>
#include <hip/hip_bf16.h>
#include <cstdint>
#include <cstddef>

#define B_ROWS 16384
#define D_DIM  256
#define TEMP_INV 14.285714285714286f   // 1/0.07

#define NITER 64      // 16-col iterations per wave (chunk = 1024 cols)

using frag_cd = __attribute__((ext_vector_type(4))) float;   // 4 fp32
using i32x4   = __attribute__((ext_vector_type(4))) int;     // one 16B chunk
using i32x8   = __attribute__((ext_vector_type(8))) int;     // 32B f8f6f4 operand

// ---------------------------------------------------------------------------
// fp8 operand storage layout (R17, verified absmax=0): fragment-major.
// row group g = row>>4, r = row&15; k-byte kappa: kt = kappa>>7,
// chunk c = (kappa&127)>>4, h = c>>2, q = c&3, b = kappa&15.
// byte offset = g*4096 + kt*2048 + h*1024 + q*256 + r*16 + b.
// MFMA 16x16x128 fp8 fragment for lane (quad,l15): chunks c=quad (h0) and
// c=quad+4 (h1) of row l15's kt-slab == slab_base + lane*16 (+1024).
// => every fragment load is one contiguous 1KB wave load (global_load_dwordx4).
// ---------------------------------------------------------------------------

// Kernel 1 (R18, verified): one block per 16-row group; 16 lanes/row norms,
// fragment-major fp8 pack via small LDS buffer, coalesced uint4 stores.
// Also zero-initializes row_sums/col_sums/out.
__global__ __launch_bounds__(256) void norm_diag_kernel(
    const float* __restrict__ q, const float* __restrict__ d,
    unsigned int* __restrict__ qn, unsigned int* __restrict__ dn,
    float* __restrict__ diag,
    float* __restrict__ row_sums, float* __restrict__ col_sums,
    float* __restrict__ out) {
    const int b = blockIdx.x;   // group index, 0..1023
    if (b < 64)            row_sums[b * 256 + threadIdx.x] = 0.0f;
    else if (b < 128)      col_sums[(b - 64) * 256 + threadIdx.x] = 0.0f;
    else if (b == 128 && threadIdx.x == 0) out[0] = 0.0f;

    const int t    = threadIdx.x;
    const int lane = t & 63;
    const int w    = t >> 6;
    const int l15  = lane & 15;
    const int rw   = lane >> 4;          // row within wave's 4
    const int r    = w * 4 + rw;         // row & 15 (0..15)
    const int row  = b * 16 + r;

    const float4* qr = (const float4*)(q + (size_t)row * D_DIM);
    const float4* dr = (const float4*)(d + (size_t)row * D_DIM);
    float4 qv[4], dv[4];
    float qss = 0.f, dss = 0.f, qd = 0.f;
#pragma unroll
    for (int p = 0; p < 4; ++p) {
        qv[p] = qr[l15 + 16 * p];
        dv[p] = dr[l15 + 16 * p];
        qss += qv[p].x*qv[p].x + qv[p].y*qv[p].y + qv[p].z*qv[p].z + qv[p].w*qv[p].w;
        dss += dv[p].x*dv[p].x + dv[p].y*dv[p].y + dv[p].z*dv[p].z + dv[p].w*dv[p].w;
        qd  += qv[p].x*dv[p].x + qv[p].y*dv[p].y + qv[p].z*dv[p].z + qv[p].w*dv[p].w;
    }
#pragma unroll
    for (int off = 1; off < 16; off <<= 1) {
        qss += __shfl_xor(qss, off);
        dss += __shfl_xor(dss, off);
        qd  += __shfl_xor(qd,  off);
    }
    const float qinv = 1.0f / fmaxf(sqrtf(qss), 1e-12f);
    const float dinv = 1.0f / fmaxf(sqrtf(dss), 1e-12f);

    __shared__ unsigned int qbuf[1024], dbuf[1024];
#pragma unroll
    for (int p = 0; p < 4; ++p) {
        const int jw = l15 + 16 * p;     // word index in row, 0..63 (kappa=4*jw)
        int qp = 0, dp = 0;
        qp = __builtin_amdgcn_cvt_pk_fp8_f32(qv[p].x * qinv, qv[p].y * qinv, qp, false);
        qp = __builtin_amdgcn_cvt_pk_fp8_f32(qv[p].z * qinv, qv[p].w * qinv, qp, true);
        dp = __builtin_amdgcn_cvt_pk_fp8_f32(dv[p].x * dinv, dv[p].y * dinv, dp, false);
        dp = __builtin_amdgcn_cvt_pk_fp8_f32(dv[p].z * dinv, dv[p].w * dinv, dp, true);
        const int c    = (jw & 31) >> 2;
        const int widx = ((jw >> 5) << 9) | ((c >> 2) << 8) | ((c & 3) << 6)
                       | (r << 2) | (jw & 3);
        qbuf[widx] = (unsigned int)qp;
        dbuf[widx] = (unsigned int)dp;
    }
    if (l15 == 0) diag[row] = qd * qinv * dinv * TEMP_INV;
    __syncthreads();
    ((uint4*)qn)[(size_t)b * 256 + t] = ((const uint4*)qbuf)[t];
    ((uint4*)dn)[(size_t)b * 256 + t] = ((const uint4*)dbuf)[t];
}

// Kernel 2 (R25): single-wave blocks, NO LDS, NO barriers, 64x16 wave tile.
// R24 post-mortem: MfmaUtil ~ 1-(0.86)^N with N=3 waves/SIMD -- each wave's
// iter span ~2000cyc holds only ~277cyc MFMA demand (14% duty). The 64x64
// tile pins 128+ regs -> 3 waves/SIMD ceiling -> ~35% MfmaUtil ceiling, and
// LDS-read bytes are conserved at ~20us. Fix: shrink the ITER (not the M-tile)
// to 16 cols -> acc 16 regs; B comes global->VGPR from the fragment-major
// layout (4 coalesced dwordx4/iter, L2-resident 512KB/XCD slab, 25TB/s < L2
// ceiling). Zero barriers -> 4096 independent waves self-stagger; per-iter
// issue ~250cyc with MFMA 69 / trans 64 / VALU ~60 -> per-wave MFMA duty 28%,
// x3 waves/SIMD = 83% pipe demand; balanced trans/VALU. Hand-peeled 3-buffer
// rotation (named b0/b1/b2, no runtime indexing - rule #20), depth-2 prefetch
// (~500cyc > L2 latency); compiler emits counted vmcnt on first use.
// Regs: A 64 + B 48 + rvu 16 + acc 16 + misc ~15 ~ 160 <= 170 cap (64,3).
__global__ __launch_bounds__(64, 3) void gemm_lse_kernel(
    const unsigned char* __restrict__ qn, const unsigned char* __restrict__ dn,
    float* __restrict__ row_sums, float* __restrict__ col_sums) {
    const int lane = threadIdx.x;     // 64-thread block = one wave
    const int l15  = lane & 15;
    const int quad = lane >> 4;

    // Grid: 4096 waves = 8 xcd x 2 chunk-sub x 256 row-strips; 2 chunks/XCD.
    const int id    = blockIdx.x;
    const int xcd   = id & 7;
    const int i     = id >> 3;              // 0..511
    const int chunk = (xcd << 1) | (i & 1); // 0..15
    const int strip = i >> 1;               // 0..255
    const int rowBase = strip * 64;
    const int colChunkBase = chunk * 1024;

    union OpU { i32x8 v; i32x4 h[2]; };

    // ---- Persistent A: 8 frags (4 mi x 2 kt) = 64 VGPRs, 16 coalesced loads.
    const unsigned char* aB = qn + (size_t)strip * 16384 + lane * 16;
    OpU a8[4][2];
#pragma unroll
    for (int mi = 0; mi < 4; ++mi)
#pragma unroll
        for (int kt = 0; kt < 2; ++kt) {
            a8[mi][kt].h[0] = *(const i32x4*)(aB + mi * 4096 + kt * 2048);
            a8[mi][kt].h[1] = *(const i32x4*)(aB + mi * 4096 + kt * 2048 + 1024);
        }

    // ---- B stream: iter it = one 16-col group at bG + it*4096 (4KB slab).
    const unsigned char* bG = dn + ((size_t)(colChunkBase >> 4) << 12) + lane * 16;

    OpU b0k0, b0k1, b1k0, b1k1, b2k0, b2k1;   // 3-deep rotation, 48 VGPRs

#define LOADB(BK0, BK1, j)                                                    \
    if ((j) < NITER) {                                                         \
        const unsigned char* p_ = bG + (size_t)(j) * 4096;                     \
        BK0.h[0] = *(const i32x4*)(p_);                                        \
        BK0.h[1] = *(const i32x4*)(p_ + 1024);                                 \
        BK1.h[0] = *(const i32x4*)(p_ + 2048);                                 \
        BK1.h[1] = *(const i32x4*)(p_ + 3072);                                 \
    }

    const float C2 = TEMP_INV * 1.44269504088896f;
    const frag_cd zf = (frag_cd){0.f, 0.f, 0.f, 0.f};

    union RV { frag_cd v[4]; float f[16]; } rvu;   // per-row exp-sum accumulators
#pragma unroll
    for (int k = 0; k < 4; ++k) rvu.v[k] = (frag_cd){0.f, 0.f, 0.f, 0.f};

    // Body: 8 MFMA on (BK0,BK1) + fused epilogue for iter 'it'.
    // C frag layout: lane holds col = colChunkBase + it*16 + l15,
    //                row = rowBase + mi*16 + quad*4 + rr.
#define BODY(BK0, BK1, it)                                                    \
    {                                                                          \
        frag_cd acc[4];                                                        \
        __builtin_amdgcn_s_setprio(1);                                         \
        _Pragma("unroll")                                                      \
        for (int mi = 0; mi < 4; ++mi)                                         \
            acc[mi] = __builtin_amdgcn_mfma_scale_f32_16x16x128_f8f6f4(        \
                a8[mi][0].v, BK0.v, zf, 0, 0, 0, 0x7F7F7F7F, 0, 0x7F7F7F7F);   \
        _Pragma("unroll")                                                      \
        for (int mi = 0; mi < 4; ++mi)                                         \
            acc[mi] = __builtin_amdgcn_mfma_scale_f32_16x16x128_f8f6f4(        \
                a8[mi][1].v, BK1.v, acc[mi], 0, 0, 0, 0x7F7F7F7F, 0,           \
                0x7F7F7F7F);                                                   \
        __builtin_amdgcn_s_setprio(0);                                         \
        float cv = 0.f;                                                        \
        _Pragma("unroll")                                                      \
        for (int mi = 0; mi < 4; ++mi) {                                       \
            const frag_cd tt = acc[mi] * C2 - C2;                              \
            frag_cd e;                                                         \
            _Pragma("unroll")                                                  \
            for (int rr = 0; rr < 4; ++rr)                                     \
                e[rr] = __builtin_amdgcn_exp2f(tt[rr]);                        \
            rvu.v[mi] += e;                                                    \
            cv += (e[0] + e[1]) + (e[2] + e[3]);                               \
        }                                                                      \
        cv += __shfl_xor(cv, 16);                                              \
        cv += __shfl_xor(cv, 32);                                              \
        if (quad == 0)                                                         \
            atomicAdd(&col_sums[colChunkBase + (it) * 16 + l15], cv);          \
    }

    // Prologue: prefetch iters 0 and 1 (depth 2).
    LOADB(b0k0, b0k1, 0)
    LOADB(b1k0, b1k1, 1)

    // Hand-peeled 3-phase rotation: compute it uses buffer (it%3); each body
    // prefetches it+3 right after its buffer is consumed. NITER=64 = 21*3 + 1.
#pragma unroll 1
    for (int base = 0; base < NITER - 1; base += 3) {
        LOADB(b2k0, b2k1, base + 2)
        BODY(b0k0, b0k1, base)
        LOADB(b0k0, b0k1, base + 3)
        BODY(b1k0, b1k1, base + 1)
        LOADB(b1k0, b1k1, base + 4)
        BODY(b2k0, b2k1, base + 2)
    }
    BODY(b0k0, b0k1, NITER - 1)   // 63 % 3 == 0 -> b0 (loaded at base=60)

#undef LOADB
#undef BODY

    // ---- final row butterfly all-reduce over the 16 lanes of each quad ----
    // 16 row partials (p = mi*4+rr); end: f[0] <-> p = l15.
#pragma unroll
    for (int s = 0; s < 4; ++s) {
        const bool bb = (l15 >> s) & 1;
#pragma unroll
        for (int k = 0; k < (8 >> s); ++k) {
            const float a0 = rvu.f[2 * k], a1 = rvu.f[2 * k + 1];
            const float keep = bb ? a1 : a0;
            const float send = bb ? a0 : a1;
            rvu.f[k] = keep + __shfl_xor(send, 1 << s);
        }
    }
    atomicAdd(&row_sums[rowBase + (l15 >> 2) * 16 + quad * 4 + (l15 & 3)],
              rvu.f[0]);
}

// Kernel 3 (parallel): each block reduces 256 rows, atomicAdd into zeroed out[0].
__global__ __launch_bounds__(256) void finalize_kernel(
    const float* __restrict__ rs, const float* __restrict__ cs,
    const float* __restrict__ dg, float* __restrict__ out) {
    const int i = blockIdx.x * 256 + threadIdx.x;
    float s = logf(rs[i]) + logf(cs[i]) - 2.0f * dg[i];
#pragma unroll
    for (int off = 32; off; off >>= 1) s += __shfl_down(s, off);
    __shared__ float buf[4];
    if ((threadIdx.x & 63) == 0) buf[threadIdx.x >> 6] = s;
    __syncthreads();
    if (threadIdx.x == 0) {
        float tot = (buf[0] + buf[1] + buf[2] + buf[3]) / (2.0f * B_ROWS);
        if (blockIdx.x == 0) tot += TEMP_INV;   // undo the fixed exp shift
        atomicAdd(out, tot);
    }
}

extern "C" void kernel_launch(void* const* d_in, const int* in_sizes, int n_in,
                              void* d_out, int out_size, void* d_ws, size_t ws_size,
                              hipStream_t stream) {
    const float* q = (const float*)d_in[0];
    const float* d = (const float*)d_in[1];
    float* out = (float*)d_out;

    char* ws = (char*)d_ws;
    unsigned char* qn = (unsigned char*)ws;                         // 4 MB fp8 (fragment-major)
    unsigned char* dn = qn + (size_t)B_ROWS * D_DIM;                // 4 MB fp8 (fragment-major)
    float* row_sums = (float*)(ws + 2 * (size_t)B_ROWS * D_DIM);
    float* col_sums = row_sums + B_ROWS;
    float* diag     = col_sums + B_ROWS;

    norm_diag_kernel<<<B_ROWS / 16, 256, 0, stream>>>(
        q, d, (unsigned int*)qn, (unsigned int*)dn, diag, row_sums, col_sums, out);
    gemm_lse_kernel<<<(B_ROWS / 64) * (B_ROWS / 1024), 64, 0, stream>>>(
        qn, dn, row_sums, col_sums);
    finalize_kernel<<<B_ROWS / 256, 256, 0, stream>>>(row_sums, col_sums, diag, out);
}

// Round 11
// 216.838 us; speedup vs baseline: 1.5778x; 1.5778x over previous
//
#include <hip/hip_runtime.h>
#include <hip/hip_bf16.h>
#include <cstdint>
#include <cstddef>

#define B_ROWS 16384
#define D_DIM  256
#define TEMP_INV 14.285714285714286f   // 1/0.07

#define NITER 16      // 64-col iterations per block (chunk = 1024 cols)

using frag_cd = __attribute__((ext_vector_type(4))) float;   // 4 fp32
using i32x4   = __attribute__((ext_vector_type(4))) int;     // one 16B chunk
using i32x8   = __attribute__((ext_vector_type(8))) int;     // 32B f8f6f4 operand

__device__ __forceinline__ void gld_lds16(const void* g, void* l) {
    __builtin_amdgcn_global_load_lds(
        (const __attribute__((address_space(1))) void*)g,
        (__attribute__((address_space(3))) void*)l,
        16, 0, 0);
}

// ---------------------------------------------------------------------------
// fp8 operand storage layout (R17, verified absmax=0): fragment-major.
// row group g = row>>4, r = row&15; k-byte kappa: kt = kappa>>7,
// chunk c = (kappa&127)>>4, h = c>>2, q = c&3, b = kappa&15.
// byte offset = g*4096 + kt*2048 + h*1024 + q*256 + r*16 + b.
// MFMA 16x16x128 fp8 fragment for lane (quad,l15): chunks c=quad (h0) and
// c=quad+4 (h1) of row l15's kt-slab == slab_base + lane*16 (+1024).
// => fragment load = one contiguous 1KB wave load; 64-col slab = 16KB linear.
// ---------------------------------------------------------------------------

// Kernel 1 (R18, verified): one block per 16-row group; 16 lanes/row norms,
// fragment-major fp8 pack via small LDS buffer, coalesced uint4 stores.
// Also zero-initializes row_sums/col_sums/out.
__global__ __launch_bounds__(256) void norm_diag_kernel(
    const float* __restrict__ q, const float* __restrict__ d,
    unsigned int* __restrict__ qn, unsigned int* __restrict__ dn,
    float* __restrict__ diag,
    float* __restrict__ row_sums, float* __restrict__ col_sums,
    float* __restrict__ out) {
    const int b = blockIdx.x;   // group index, 0..1023
    if (b < 64)            row_sums[b * 256 + threadIdx.x] = 0.0f;
    else if (b < 128)      col_sums[(b - 64) * 256 + threadIdx.x] = 0.0f;
    else if (b == 128 && threadIdx.x == 0) out[0] = 0.0f;

    const int t    = threadIdx.x;
    const int lane = t & 63;
    const int w    = t >> 6;
    const int l15  = lane & 15;
    const int rw   = lane >> 4;          // row within wave's 4
    const int r    = w * 4 + rw;         // row & 15 (0..15)
    const int row  = b * 16 + r;

    const float4* qr = (const float4*)(q + (size_t)row * D_DIM);
    const float4* dr = (const float4*)(d + (size_t)row * D_DIM);
    float4 qv[4], dv[4];
    float qss = 0.f, dss = 0.f, qd = 0.f;
#pragma unroll
    for (int p = 0; p < 4; ++p) {
        qv[p] = qr[l15 + 16 * p];
        dv[p] = dr[l15 + 16 * p];
        qss += qv[p].x*qv[p].x + qv[p].y*qv[p].y + qv[p].z*qv[p].z + qv[p].w*qv[p].w;
        dss += dv[p].x*dv[p].x + dv[p].y*dv[p].y + dv[p].z*dv[p].z + dv[p].w*dv[p].w;
        qd  += qv[p].x*dv[p].x + qv[p].y*dv[p].y + qv[p].z*dv[p].z + qv[p].w*dv[p].w;
    }
#pragma unroll
    for (int off = 1; off < 16; off <<= 1) {
        qss += __shfl_xor(qss, off);
        dss += __shfl_xor(dss, off);
        qd  += __shfl_xor(qd,  off);
    }
    const float qinv = 1.0f / fmaxf(sqrtf(qss), 1e-12f);
    const float dinv = 1.0f / fmaxf(sqrtf(dss), 1e-12f);

    __shared__ unsigned int qbuf[1024], dbuf[1024];
#pragma unroll
    for (int p = 0; p < 4; ++p) {
        const int jw = l15 + 16 * p;     // word index in row, 0..63 (kappa=4*jw)
        int qp = 0, dp = 0;
        qp = __builtin_amdgcn_cvt_pk_fp8_f32(qv[p].x * qinv, qv[p].y * qinv, qp, false);
        qp = __builtin_amdgcn_cvt_pk_fp8_f32(qv[p].z * qinv, qv[p].w * qinv, qp, true);
        dp = __builtin_amdgcn_cvt_pk_fp8_f32(dv[p].x * dinv, dv[p].y * dinv, dp, false);
        dp = __builtin_amdgcn_cvt_pk_fp8_f32(dv[p].z * dinv, dv[p].w * dinv, dp, true);
        const int c    = (jw & 31) >> 2;
        const int widx = ((jw >> 5) << 9) | ((c >> 2) << 8) | ((c & 3) << 6)
                       | (r << 2) | (jw & 3);
        qbuf[widx] = (unsigned int)qp;
        dbuf[widx] = (unsigned int)dp;
    }
    if (l15 == 0) diag[row] = qd * qinv * dinv * TEMP_INV;
    __syncthreads();
    ((uint4*)qn)[(size_t)b * 256 + t] = ((const uint4*)qbuf)[t];
    ((uint4*)dn)[(size_t)b * 256 + t] = ((const uint4*)dbuf)[t];
}

// Kernel 2 (R26): R20 structure (best measured: 85us) with ONE change:
// __launch_bounds__(256,3) -- cap unified VGPR+AGPR at 512/3=170 regs.
// R20 allocated 104 VGPR + 64 AGPR = 168 under the lax (256,2) cap, and
// residency landed at 2 blocks/CU (Occupancy 18.7%). Demand 168 <= 170, so
// the tighter cap should fit WITHOUT spills -> 3 waves/SIMD -> 3 blocks/CU
// (LDS 48KB x 3 = 144KB <= 160KB). Work per CU fixed; residency x1.5 gives
// proportionally more cross-wave overlap (even the pessimistic sum-model
// predicts 85 x 2/3 ~ 63us; MFMA pipe then ~50% duty, not yet saturated).
// R25 lesson (3rd repeat): no-LDS/all-reg paths get rematerialized by the
// compiler -> A-in-regs + B-via-LDS is the only structure where the A panel
// provably stays resident (FETCH constant 18.5MB, VGPR ~100).
__global__ __launch_bounds__(256, 3) void gemm_lse_kernel(
    const unsigned char* __restrict__ qn, const unsigned char* __restrict__ dn,
    float* __restrict__ row_sums, float* __restrict__ col_sums) {
    __shared__ unsigned char ldsB[3][16384];   // 48 KB: 3 x (64 cols x 256 K)

    const int t    = threadIdx.x;
    const int lane = t & 63;
    const int w    = t >> 6;          // 0..3 : which 64-row strip
    const int l15  = lane & 15;
    const int quad = lane >> 4;

    // Grid: 1024 blocks = 64 row-groups x 16 col-chunks; 2 chunks per XCD.
    const int id   = blockIdx.x;
    const int xcd  = id & 7;
    const int i    = id >> 3;               // 0..127
    const int chunk   = (xcd << 1) | (i & 1);   // 0..15
    const int rowg    = i >> 1;                 // 0..63
    const int rowBase = rowg * 256;
    const int colChunkBase = chunk * 1024;

    union OpU { i32x8 v; i32x4 h[2]; };

    // ---- Persistent A: 8 frags (4 mi x 2 kt) = 64 VGPRs, 16 coalesced loads.
    const unsigned char* aB = qn + ((size_t)((rowBase >> 4) + w * 4) << 12) + lane * 16;
    OpU a8[4][2];
#pragma unroll
    for (int mi = 0; mi < 4; ++mi)
#pragma unroll
        for (int kt = 0; kt < 2; ++kt) {
            a8[mi][kt].h[0] = *(const i32x4*)(aB + mi * 4096 + kt * 2048);
            a8[mi][kt].h[1] = *(const i32x4*)(aB + mi * 4096 + kt * 2048 + 1024);
        }

    // ---- B stream: iter it occupies 16KB linear slab at bG + it*16384.
    const unsigned char* bG = dn + ((size_t)(colChunkBase >> 4) << 12);

    // Stage iter j -> buffer buf (16KB linear copy; LDS dest = uniform base
    // + lane*size as required by global_load_lds). 4 loads/thread/stage.
#define STAGE(bufidx, j)                                                      \
    {                                                                          \
        const unsigned char* gsrc = bG + (size_t)(j) * 16384;                  \
        unsigned char* ldst = &ldsB[bufidx][0];                                \
        _Pragma("unroll")                                                      \
        for (int ii = 0; ii < 4; ++ii)                                         \
            gld_lds16(gsrc + ii * 4096 + t * 16, ldst + ii * 4096 + t * 16);   \
    }

    // Prologue: stage iters 0 and 1 (8 loads in flight per thread).
    STAGE(0, 0)
    STAGE(1, 1)

    union RV { frag_cd v[4]; float f[16]; } rvu;   // per-row exp-sum accumulators
#pragma unroll
    for (int k = 0; k < 4; ++k) rvu.v[k] = (frag_cd){0.f, 0.f, 0.f, 0.f};

    const float C2 = TEMP_INV * 1.44269504088896f;
    const frag_cd zf = (frag_cd){0.f, 0.f, 0.f, 0.f};

    int cur = 0;   // buffer holding iter it
#pragma unroll 1
    for (int it = 0; it < NITER; ++it) {
        // Wait for iter it's 4 loads (leave later stages in flight); barrier
        // doubles as "all waves finished iter it-1" (overwrite safety).
        if (it == NITER - 1) asm volatile("s_waitcnt vmcnt(0)" ::: "memory");
        else                 asm volatile("s_waitcnt vmcnt(4)" ::: "memory");
        __builtin_amdgcn_s_barrier();
        asm volatile("" ::: "memory");

        // Stage iter it+2 into the buffer freed at iter it-1.
        const int nxt = (cur + 2 >= 3) ? cur - 1 : cur + 2;
        if (it + 2 < NITER) STAGE(nxt, it + 2)

        const unsigned char* bL = &ldsB[cur][0] + lane * 16;

        frag_cd acc[4][4];

        // kt0: 4 B frags from LDS, 16 MFMA (C = zero, no acc init needed)
        {
            OpU b8[4];
#pragma unroll
            for (int ni = 0; ni < 4; ++ni) {
                b8[ni].h[0] = *(const i32x4*)(bL + ni * 4096);
                b8[ni].h[1] = *(const i32x4*)(bL + ni * 4096 + 1024);
            }
            __builtin_amdgcn_s_setprio(1);
#pragma unroll
            for (int mi = 0; mi < 4; ++mi)
#pragma unroll
                for (int ni = 0; ni < 4; ++ni)
                    acc[mi][ni] = __builtin_amdgcn_mfma_scale_f32_16x16x128_f8f6f4(
                        a8[mi][0].v, b8[ni].v, zf,
                        0, 0, 0, 0x7F7F7F7F, 0, 0x7F7F7F7F);
            __builtin_amdgcn_s_setprio(0);
        }
        // kt1: 4 B frags, 16 MFMA
        {
            OpU b8[4];
#pragma unroll
            for (int ni = 0; ni < 4; ++ni) {
                b8[ni].h[0] = *(const i32x4*)(bL + ni * 4096 + 2048);
                b8[ni].h[1] = *(const i32x4*)(bL + ni * 4096 + 2048 + 1024);
            }
            __builtin_amdgcn_s_setprio(1);
#pragma unroll
            for (int mi = 0; mi < 4; ++mi)
#pragma unroll
                for (int ni = 0; ni < 4; ++ni)
                    acc[mi][ni] = __builtin_amdgcn_mfma_scale_f32_16x16x128_f8f6f4(
                        a8[mi][1].v, b8[ni].v, acc[mi][ni],
                        0, 0, 0, 0x7F7F7F7F, 0, 0x7F7F7F7F);
            __builtin_amdgcn_s_setprio(0);
        }

        // ---- per-iter epilogue ----
        // C frag layout: lane holds col = colChunkBase + it*64 + ni*16 + l15,
        //                row = rowBase + w*64 + mi*16 + quad*4 + rr.
        float cv[4] = {0.f, 0.f, 0.f, 0.f};
#pragma unroll
        for (int mi = 0; mi < 4; ++mi)
#pragma unroll
            for (int ni = 0; ni < 4; ++ni) {
                const frag_cd tt = acc[mi][ni] * C2 - C2;   // v_pk_fma_f32 x2
                frag_cd e;
#pragma unroll
                for (int rr = 0; rr < 4; ++rr) e[rr] = __builtin_amdgcn_exp2f(tt[rr]);
                rvu.v[mi] += e;                              // row partials
                cv[ni] += (e[0] + e[1]) + (e[2] + e[3]);     // col partial (scalar)
            }

        // col butterfly over the 4 quads; end: cv[0] <-> ni = quad
#pragma unroll
        for (int s = 0; s < 2; ++s) {
            const bool bb = (quad >> s) & 1;
#pragma unroll
            for (int k = 0; k < (2 >> s); ++k) {
                const float a0 = cv[2 * k], a1 = cv[2 * k + 1];
                const float keep = bb ? a1 : a0;
                const float send = bb ? a0 : a1;
                cv[k] = keep + __shfl_xor(send, 16 << s);
            }
        }
        atomicAdd(&col_sums[colChunkBase + it * 64 + quad * 16 + l15], cv[0]);

        cur = (cur + 1 >= 3) ? 0 : cur + 1;
    }
#undef STAGE

    // ---- final row butterfly all-reduce over the 16 lanes of each quad ----
    // 16 row partials (p = mi*4+rr); end: f[0] <-> p = l15.
#pragma unroll
    for (int s = 0; s < 4; ++s) {
        const bool bb = (l15 >> s) & 1;
#pragma unroll
        for (int k = 0; k < (8 >> s); ++k) {
            const float a0 = rvu.f[2 * k], a1 = rvu.f[2 * k + 1];
            const float keep = bb ? a1 : a0;
            const float send = bb ? a0 : a1;
            rvu.f[k] = keep + __shfl_xor(send, 1 << s);
        }
    }
    atomicAdd(&row_sums[rowBase + w * 64 + (l15 >> 2) * 16 + quad * 4 + (l15 & 3)],
              rvu.f[0]);
}

// Kernel 3 (parallel): each block reduces 256 rows, atomicAdd into zeroed out[0].
__global__ __launch_bounds__(256) void finalize_kernel(
    const float* __restrict__ rs, const float* __restrict__ cs,
    const float* __restrict__ dg, float* __restrict__ out) {
    const int i = blockIdx.x * 256 + threadIdx.x;
    float s = logf(rs[i]) + logf(cs[i]) - 2.0f * dg[i];
#pragma unroll
    for (int off = 32; off; off >>= 1) s += __shfl_down(s, off);
    __shared__ float buf[4];
    if ((threadIdx.x & 63) == 0) buf[threadIdx.x >> 6] = s;
    __syncthreads();
    if (threadIdx.x == 0) {
        float tot = (buf[0] + buf[1] + buf[2] + buf[3]) / (2.0f * B_ROWS);
        if (blockIdx.x == 0) tot += TEMP_INV;   // undo the fixed exp shift
        atomicAdd(out, tot);
    }
}

extern "C" void kernel_launch(void* const* d_in, const int* in_sizes, int n_in,
                              void* d_out, int out_size, void* d_ws, size_t ws_size,
                              hipStream_t stream) {
    const float* q = (const float*)d_in[0];
    const float* d = (const float*)d_in[1];
    float* out = (float*)d_out;

    char* ws = (char*)d_ws;
    unsigned char* qn = (unsigned char*)ws;                         // 4 MB fp8 (fragment-major)
    unsigned char* dn = qn + (size_t)B_ROWS * D_DIM;                // 4 MB fp8 (fragment-major)
    float* row_sums = (float*)(ws + 2 * (size_t)B_ROWS * D_DIM);
    float* col_sums = row_sums + B_ROWS;
    float* diag     = col_sums + B_ROWS;

    norm_diag_kernel<<<B_ROWS / 16, 256, 0, stream>>>(
        q, d, (unsigned int*)qn, (unsigned int*)dn, diag, row_sums, col_sums, out);
    gemm_lse_kernel<<<(B_ROWS / 256) * (B_ROWS / 1024), 256, 0, stream>>>(
        qn, dn, row_sums, col_sums);
    finalize_kernel<<<B_ROWS / 256, 256, 0, stream>>>(row_sums, col_sums, diag, out);
}

// Round 12
// 148.423 us; speedup vs baseline: 2.3051x; 1.4609x over previous
//
#include <hip/hip_runtime.h>
#include <hip/hip_bf16.h>
#include <cstdint>
#include <cstddef>

#define B_ROWS 16384
#define D_DIM  256
#define TEMP_INV 14.285714285714286f   // 1/0.07

#define NITER 16      // 64-col iterations per block (chunk = 1024 cols)

using frag_cd = __attribute__((ext_vector_type(4))) float;   // 4 fp32
using i32x4   = __attribute__((ext_vector_type(4))) int;     // one 16B chunk
using i32x8   = __attribute__((ext_vector_type(8))) int;     // 32B f8f6f4 operand

__device__ __forceinline__ void gld_lds16(const void* g, void* l) {
    __builtin_amdgcn_global_load_lds(
        (const __attribute__((address_space(1))) void*)g,
        (__attribute__((address_space(3))) void*)l,
        16, 0, 0);
}

// ---------------------------------------------------------------------------
// fp8 operand storage layout (R17, verified absmax=0): fragment-major.
// row group g = row>>4, r = row&15; k-byte kappa: kt = kappa>>7,
// chunk c = (kappa&127)>>4, h = c>>2, q = c&3, b = kappa&15.
// byte offset = g*4096 + kt*2048 + h*1024 + q*256 + r*16 + b.
// MFMA 16x16x128 fp8 fragment for lane (quad,l15): chunks c=quad (h0) and
// c=quad+4 (h1) of row l15's kt-slab == slab_base + lane*16 (+1024).
// => fragment load = one contiguous 1KB wave load; 64-col slab = 16KB linear.
// ---------------------------------------------------------------------------

// Kernel 1 (R18, verified): one block per 16-row group; 16 lanes/row norms,
// fragment-major fp8 pack via small LDS buffer, coalesced uint4 stores.
// Also zero-initializes row_sums/col_sums/out.
__global__ __launch_bounds__(256) void norm_diag_kernel(
    const float* __restrict__ q, const float* __restrict__ d,
    unsigned int* __restrict__ qn, unsigned int* __restrict__ dn,
    float* __restrict__ diag,
    float* __restrict__ row_sums, float* __restrict__ col_sums,
    float* __restrict__ out) {
    const int b = blockIdx.x;   // group index, 0..1023
    if (b < 64)            row_sums[b * 256 + threadIdx.x] = 0.0f;
    else if (b < 128)      col_sums[(b - 64) * 256 + threadIdx.x] = 0.0f;
    else if (b == 128 && threadIdx.x == 0) out[0] = 0.0f;

    const int t    = threadIdx.x;
    const int lane = t & 63;
    const int w    = t >> 6;
    const int l15  = lane & 15;
    const int rw   = lane >> 4;          // row within wave's 4
    const int r    = w * 4 + rw;         // row & 15 (0..15)
    const int row  = b * 16 + r;

    const float4* qr = (const float4*)(q + (size_t)row * D_DIM);
    const float4* dr = (const float4*)(d + (size_t)row * D_DIM);
    float4 qv[4], dv[4];
    float qss = 0.f, dss = 0.f, qd = 0.f;
#pragma unroll
    for (int p = 0; p < 4; ++p) {
        qv[p] = qr[l15 + 16 * p];
        dv[p] = dr[l15 + 16 * p];
        qss += qv[p].x*qv[p].x + qv[p].y*qv[p].y + qv[p].z*qv[p].z + qv[p].w*qv[p].w;
        dss += dv[p].x*dv[p].x + dv[p].y*dv[p].y + dv[p].z*dv[p].z + dv[p].w*dv[p].w;
        qd  += qv[p].x*dv[p].x + qv[p].y*dv[p].y + qv[p].z*dv[p].z + qv[p].w*dv[p].w;
    }
#pragma unroll
    for (int off = 1; off < 16; off <<= 1) {
        qss += __shfl_xor(qss, off);
        dss += __shfl_xor(dss, off);
        qd  += __shfl_xor(qd,  off);
    }
    const float qinv = 1.0f / fmaxf(sqrtf(qss), 1e-12f);
    const float dinv = 1.0f / fmaxf(sqrtf(dss), 1e-12f);

    __shared__ unsigned int qbuf[1024], dbuf[1024];
#pragma unroll
    for (int p = 0; p < 4; ++p) {
        const int jw = l15 + 16 * p;     // word index in row, 0..63 (kappa=4*jw)
        int qp = 0, dp = 0;
        qp = __builtin_amdgcn_cvt_pk_fp8_f32(qv[p].x * qinv, qv[p].y * qinv, qp, false);
        qp = __builtin_amdgcn_cvt_pk_fp8_f32(qv[p].z * qinv, qv[p].w * qinv, qp, true);
        dp = __builtin_amdgcn_cvt_pk_fp8_f32(dv[p].x * dinv, dv[p].y * dinv, dp, false);
        dp = __builtin_amdgcn_cvt_pk_fp8_f32(dv[p].z * dinv, dv[p].w * dinv, dp, true);
        const int c    = (jw & 31) >> 2;
        const int widx = ((jw >> 5) << 9) | ((c >> 2) << 8) | ((c & 3) << 6)
                       | (r << 2) | (jw & 3);
        qbuf[widx] = (unsigned int)qp;
        dbuf[widx] = (unsigned int)dp;
    }
    if (l15 == 0) diag[row] = qd * qinv * dinv * TEMP_INV;
    __syncthreads();
    ((uint4*)qn)[(size_t)b * 256 + t] = ((const uint4*)qbuf)[t];
    ((uint4*)dn)[(size_t)b * 256 + t] = ((const uint4*)dbuf)[t];
}

// Kernel 2 (R27): R20 structure with the register DEMAND cut to fit 3
// waves/SIMD (instead of R26's failed attempt to squeeze the cap).
// R26 post-mortem: demand 168 > cap 170-overhead -> allocator rematerialized
// the A panel (FETCH 18.5->66MB, gemm 148us). Rule: cap must exceed demand
// WITH MARGIN. Here each iter is split into two 32-col halves: acc[4][2]=32
// AGPR (was 64), b8[2]=16 VGPR (was 32) -> demand ~ A 64 + acc 32 + b8 16 +
// rvu 16 + cv 4 + addr ~12 = 144 <= 170 with ~26 margin. MFMA count, LDS
// bytes, trans ops unchanged. LDS 48KB x 3 blocks = 144KB <= 160 -> 3
// blocks/CU, 3 waves/SIMD. Discriminator: FETCH_SIZE must stay ~18.5MB.
__global__ __launch_bounds__(256, 3) void gemm_lse_kernel(
    const unsigned char* __restrict__ qn, const unsigned char* __restrict__ dn,
    float* __restrict__ row_sums, float* __restrict__ col_sums) {
    __shared__ unsigned char ldsB[3][16384];   // 48 KB: 3 x (64 cols x 256 K)

    const int t    = threadIdx.x;
    const int lane = t & 63;
    const int w    = t >> 6;          // 0..3 : which 64-row strip
    const int l15  = lane & 15;
    const int quad = lane >> 4;

    // Grid: 1024 blocks = 64 row-groups x 16 col-chunks; 2 chunks per XCD.
    const int id   = blockIdx.x;
    const int xcd  = id & 7;
    const int i    = id >> 3;               // 0..127
    const int chunk   = (xcd << 1) | (i & 1);   // 0..15
    const int rowg    = i >> 1;                 // 0..63
    const int rowBase = rowg * 256;
    const int colChunkBase = chunk * 1024;

    union OpU { i32x8 v; i32x4 h[2]; };

    // ---- Persistent A: 8 frags (4 mi x 2 kt) = 64 VGPRs, 16 coalesced loads.
    const unsigned char* aB = qn + ((size_t)((rowBase >> 4) + w * 4) << 12) + lane * 16;
    OpU a8[4][2];
#pragma unroll
    for (int mi = 0; mi < 4; ++mi)
#pragma unroll
        for (int kt = 0; kt < 2; ++kt) {
            a8[mi][kt].h[0] = *(const i32x4*)(aB + mi * 4096 + kt * 2048);
            a8[mi][kt].h[1] = *(const i32x4*)(aB + mi * 4096 + kt * 2048 + 1024);
        }

    // ---- B stream: iter it occupies 16KB linear slab at bG + it*16384.
    const unsigned char* bG = dn + ((size_t)(colChunkBase >> 4) << 12);

#define STAGE(bufidx, j)                                                      \
    {                                                                          \
        const unsigned char* gsrc = bG + (size_t)(j) * 16384;                  \
        unsigned char* ldst = &ldsB[bufidx][0];                                \
        _Pragma("unroll")                                                      \
        for (int ii = 0; ii < 4; ++ii)                                         \
            gld_lds16(gsrc + ii * 4096 + t * 16, ldst + ii * 4096 + t * 16);   \
    }

    // Prologue: stage iters 0 and 1 (8 loads in flight per thread).
    STAGE(0, 0)
    STAGE(1, 1)

    union RV { frag_cd v[4]; float f[16]; } rvu;   // per-row exp-sum accumulators
#pragma unroll
    for (int k = 0; k < 4; ++k) rvu.v[k] = (frag_cd){0.f, 0.f, 0.f, 0.f};

    const float C2 = TEMP_INV * 1.44269504088896f;
    const frag_cd zf = (frag_cd){0.f, 0.f, 0.f, 0.f};

    int cur = 0;   // buffer holding iter it
#pragma unroll 1
    for (int it = 0; it < NITER; ++it) {
        // Wait for iter it's 4 loads (leave later stages in flight); barrier
        // doubles as "all waves finished iter it-1" (overwrite safety).
        if (it == NITER - 1) asm volatile("s_waitcnt vmcnt(0)" ::: "memory");
        else                 asm volatile("s_waitcnt vmcnt(4)" ::: "memory");
        __builtin_amdgcn_s_barrier();
        asm volatile("" ::: "memory");

        // Stage iter it+2 into the buffer freed at iter it-1.
        const int nxt = (cur + 2 >= 3) ? cur - 1 : cur + 2;
        if (it + 2 < NITER) STAGE(nxt, it + 2)

        const unsigned char* bL = &ldsB[cur][0] + lane * 16;

        float cv[4] = {0.f, 0.f, 0.f, 0.f};

        // Two 32-col halves: acc[4][2] (32 AGPR) + b8[2] (16 VGPR) live max.
#pragma unroll
        for (int h = 0; h < 2; ++h) {
            const unsigned char* bH = bL + h * 2 * 4096;
            frag_cd acc[4][2];
            OpU b8[2];

            // kt0: 2 B frags, 8 MFMA (C = zero)
#pragma unroll
            for (int ni = 0; ni < 2; ++ni) {
                b8[ni].h[0] = *(const i32x4*)(bH + ni * 4096);
                b8[ni].h[1] = *(const i32x4*)(bH + ni * 4096 + 1024);
            }
            __builtin_amdgcn_s_setprio(1);
#pragma unroll
            for (int mi = 0; mi < 4; ++mi)
#pragma unroll
                for (int ni = 0; ni < 2; ++ni)
                    acc[mi][ni] = __builtin_amdgcn_mfma_scale_f32_16x16x128_f8f6f4(
                        a8[mi][0].v, b8[ni].v, zf,
                        0, 0, 0, 0x7F7F7F7F, 0, 0x7F7F7F7F);
            __builtin_amdgcn_s_setprio(0);

            // kt1: 2 B frags, 8 MFMA
#pragma unroll
            for (int ni = 0; ni < 2; ++ni) {
                b8[ni].h[0] = *(const i32x4*)(bH + ni * 4096 + 2048);
                b8[ni].h[1] = *(const i32x4*)(bH + ni * 4096 + 2048 + 1024);
            }
            __builtin_amdgcn_s_setprio(1);
#pragma unroll
            for (int mi = 0; mi < 4; ++mi)
#pragma unroll
                for (int ni = 0; ni < 2; ++ni)
                    acc[mi][ni] = __builtin_amdgcn_mfma_scale_f32_16x16x128_f8f6f4(
                        a8[mi][1].v, b8[ni].v, acc[mi][ni],
                        0, 0, 0, 0x7F7F7F7F, 0, 0x7F7F7F7F);
            __builtin_amdgcn_s_setprio(0);

            // epilogue for this half's 8 frags
            // C frag layout: col = colChunkBase + it*64 + (h*2+ni)*16 + l15,
            //                row = rowBase + w*64 + mi*16 + quad*4 + rr.
#pragma unroll
            for (int mi = 0; mi < 4; ++mi)
#pragma unroll
                for (int ni = 0; ni < 2; ++ni) {
                    const frag_cd tt = acc[mi][ni] * C2 - C2;   // v_pk_fma_f32 x2
                    frag_cd e;
#pragma unroll
                    for (int rr = 0; rr < 4; ++rr)
                        e[rr] = __builtin_amdgcn_exp2f(tt[rr]);
                    rvu.v[mi] += e;                              // row partials
                    cv[h * 2 + ni] += (e[0] + e[1]) + (e[2] + e[3]);
                }
        }

        // col butterfly over the 4 quads; end: cv[0] <-> ni = quad
#pragma unroll
        for (int s = 0; s < 2; ++s) {
            const bool bb = (quad >> s) & 1;
#pragma unroll
            for (int k = 0; k < (2 >> s); ++k) {
                const float a0 = cv[2 * k], a1 = cv[2 * k + 1];
                const float keep = bb ? a1 : a0;
                const float send = bb ? a0 : a1;
                cv[k] = keep + __shfl_xor(send, 16 << s);
            }
        }
        atomicAdd(&col_sums[colChunkBase + it * 64 + quad * 16 + l15], cv[0]);

        cur = (cur + 1 >= 3) ? 0 : cur + 1;
    }
#undef STAGE

    // ---- final row butterfly all-reduce over the 16 lanes of each quad ----
    // 16 row partials (p = mi*4+rr); end: f[0] <-> p = l15.
#pragma unroll
    for (int s = 0; s < 4; ++s) {
        const bool bb = (l15 >> s) & 1;
#pragma unroll
        for (int k = 0; k < (8 >> s); ++k) {
            const float a0 = rvu.f[2 * k], a1 = rvu.f[2 * k + 1];
            const float keep = bb ? a1 : a0;
            const float send = bb ? a0 : a1;
            rvu.f[k] = keep + __shfl_xor(send, 1 << s);
        }
    }
    atomicAdd(&row_sums[rowBase + w * 64 + (l15 >> 2) * 16 + quad * 4 + (l15 & 3)],
              rvu.f[0]);
}

// Kernel 3 (parallel): each block reduces 256 rows, atomicAdd into zeroed out[0].
__global__ __launch_bounds__(256) void finalize_kernel(
    const float* __restrict__ rs, const float* __restrict__ cs,
    const float* __restrict__ dg, float* __restrict__ out) {
    const int i = blockIdx.x * 256 + threadIdx.x;
    float s = logf(rs[i]) + logf(cs[i]) - 2.0f * dg[i];
#pragma unroll
    for (int off = 32; off; off >>= 1) s += __shfl_down(s, off);
    __shared__ float buf[4];
    if ((threadIdx.x & 63) == 0) buf[threadIdx.x >> 6] = s;
    __syncthreads();
    if (threadIdx.x == 0) {
        float tot = (buf[0] + buf[1] + buf[2] + buf[3]) / (2.0f * B_ROWS);
        if (blockIdx.x == 0) tot += TEMP_INV;   // undo the fixed exp shift
        atomicAdd(out, tot);
    }
}

extern "C" void kernel_launch(void* const* d_in, const int* in_sizes, int n_in,
                              void* d_out, int out_size, void* d_ws, size_t ws_size,
                              hipStream_t stream) {
    const float* q = (const float*)d_in[0];
    const float* d = (const float*)d_in[1];
    float* out = (float*)d_out;

    char* ws = (char*)d_ws;
    unsigned char* qn = (unsigned char*)ws;                         // 4 MB fp8 (fragment-major)
    unsigned char* dn = qn + (size_t)B_ROWS * D_DIM;                // 4 MB fp8 (fragment-major)
    float* row_sums = (float*)(ws + 2 * (size_t)B_ROWS * D_DIM);
    float* col_sums = row_sums + B_ROWS;
    float* diag     = col_sums + B_ROWS;

    norm_diag_kernel<<<B_ROWS / 16, 256, 0, stream>>>(
        q, d, (unsigned int*)qn, (unsigned int*)dn, diag, row_sums, col_sums, out);
    gemm_lse_kernel<<<(B_ROWS / 256) * (B_ROWS / 1024), 256, 0, stream>>>(
        qn, dn, row_sums, col_sums);
    finalize_kernel<<<B_ROWS / 256, 256, 0, stream>>>(row_sums, col_sums, diag, out);
}